// Round 14
// baseline (105.069 us; speedup 1.0000x reference)
//
#include <hip/hip_runtime.h>
#include <hip/hip_bf16.h>

#define BATCH  2
#define SEQ    2048
#define DMODEL 1024
#define NHEAD  16
#define HD     64
#define BH     (BATCH * NHEAD)

typedef __attribute__((ext_vector_type(8))) short s8v;    // 8 bf16 = 4 VGPRs (MFMA A/B frag)
typedef __attribute__((ext_vector_type(16))) float f16v;  // 32x32 MFMA C/D frag
typedef __attribute__((ext_vector_type(4))) unsigned u4v; // 4 u32 = one A-frag as words

// sqrt(0.125 * log2(e)): folded QK^T scale (beta^2 = 0.18033688)
#define QK_BETA 0.42466089f

__device__ inline unsigned short bf16_rne(float f) {
    unsigned u = __builtin_bit_cast(unsigned, f);
    u += 0x7FFFu + ((u >> 16) & 1u);
    return (unsigned short)(u >> 16);
}

// pack two f32 -> u32 of 2 bf16 via hardware v_cvt_pk_bf16_f32 (RNE).
// memcpy, not bit_cast (r5: __hip_bfloat162 not trivially copyable here).
__device__ __forceinline__ unsigned pk_bf16(float lo, float hi) {
    __hip_bfloat162 h = __float22bfloat162_rn(make_float2(lo, hi));
    unsigned u;
    __builtin_memcpy(&u, &h, 4);
    return u;
}

// half-wave exchange (pure-register VALU op, "+v" data deps, no memory).
__device__ __forceinline__ void pl32swap(unsigned& a, unsigned& b) {
    asm volatile("v_permlane32_swap_b32 %0, %1" : "+v"(a), "+v"(b));
}

// ---------------------------------------------------------------------------
// Prep v4 [verbatim r11/r13, verified passing]: x fp32 -> xb bf16 scaled by
// QK_BETA (Q/K path) and xbT bf16 unscaled [bh][d][s] (V path).
// ---------------------------------------------------------------------------
__global__ __launch_bounds__(256) void prep_kernel(const float* __restrict__ x,
                                                   unsigned short* __restrict__ xb,
                                                   unsigned short* __restrict__ xbT) {
    __shared__ unsigned short tileT[64 * 40];
    const int id = blockIdx.x;
    const int bh = id & (BH - 1);
    const int st = id >> 5;                    // s-tile 0..63
    const int b = bh >> 4, h = bh & (NHEAD - 1);
    const int s0 = st * 32;
    const int tid = threadIdx.x;
    const int c4 = tid & 15, r16 = tid >> 4;

    const size_t off0 = (size_t)(b * SEQ + s0 + r16) * DMODEL + h * HD + c4 * 4;
    const size_t off1 = (size_t)(b * SEQ + s0 + 16 + r16) * DMODEL + h * HD + c4 * 4;
    const float4 v0 = *(const float4*)(x + off0);
    const float4 v1 = *(const float4*)(x + off1);

    {
        uint2 u;
        u.x = pk_bf16(v0.x * QK_BETA, v0.y * QK_BETA);
        u.y = pk_bf16(v0.z * QK_BETA, v0.w * QK_BETA);
        *(uint2*)(xb + off0) = u;
        u.x = pk_bf16(v1.x * QK_BETA, v1.y * QK_BETA);
        u.y = pk_bf16(v1.z * QK_BETA, v1.w * QK_BETA);
        *(uint2*)(xb + off1) = u;
    }
    {
        const int d0 = c4 * 4;
        unsigned short* t0 = tileT + r16;
        t0[(d0 + 0) * 40] = bf16_rne(v0.x);
        t0[(d0 + 1) * 40] = bf16_rne(v0.y);
        t0[(d0 + 2) * 40] = bf16_rne(v0.z);
        t0[(d0 + 3) * 40] = bf16_rne(v0.w);
        unsigned short* t1 = tileT + 16 + r16;
        t1[(d0 + 0) * 40] = bf16_rne(v1.x);
        t1[(d0 + 1) * 40] = bf16_rne(v1.y);
        t1[(d0 + 2) * 40] = bf16_rne(v1.z);
        t1[(d0 + 3) * 40] = bf16_rne(v1.w);
    }
    __syncthreads();
    {
        const int d = tid >> 2;
        const int sq = (tid & 3) * 8;
        const s8v o = *(const s8v*)(tileT + d * 40 + sq);
        *(s8v*)(xbT + (size_t)(bh * HD + d) * SEQ + s0 + sq) = o;
    }
}

// ---------------------------------------------------------------------------
// Stage one 64x64 K tile + 64x64 V^T tile into LDS buffer at bufoff, 2-wave
// block: wave 0 -> K rows, wave 1 -> V^T rows. [verbatim r13, verified]
// ---------------------------------------------------------------------------
__device__ __forceinline__ void stage_tile2(const unsigned short* __restrict__ xbh,
                                            const unsigned short* __restrict__ xTh,
                                            char* lds, int bufoff, int k0,
                                            int w, int sr, int sc) {
    if (w == 0) {
#pragma unroll
        for (int i = 0; i < 8; ++i) {
            const int r = i * 8 + sr;
            const unsigned short* gsrc =
                xbh + (size_t)(k0 + r) * DMODEL + ((sc ^ (r & 7)) * 8);
            const int loff = __builtin_amdgcn_readfirstlane(bufoff + i * 1024);
            __builtin_amdgcn_global_load_lds(
                (const __attribute__((address_space(1))) void*)gsrc,
                (__attribute__((address_space(3))) void*)(lds + loff), 16, 0, 0);
        }
    } else {
#pragma unroll
        for (int i = 0; i < 8; ++i) {
            const int d = i * 8 + sr;
            const unsigned short* gsrc =
                xTh + (size_t)d * SEQ + k0 + ((sc ^ (d & 7)) * 8);
            const int loff = __builtin_amdgcn_readfirstlane(bufoff + 8192 + i * 1024);
            __builtin_amdgcn_global_load_lds(
                (const __attribute__((address_space(1))) void*)gsrc,
                (__attribute__((address_space(3))) void*)(lds + loff), 16, 0, 0);
        }
    }
}

// ---------------------------------------------------------------------------
// Flash attention, bf16 MFMA 32x32x16, swapped QK^T, in-register P (r13,
// verified), now T15 double-pipelined: iteration kt computes QK(kt) and
// stages V-frags(kt) to REGISTERS, while finishing (exp/mask/pack/permlane/
// PV, register-only) tile kt-1 — breaking the serial QK->SM->PV chain that
// r7-r13 showed is the invariant cost. Sync template byte-identical to
// r6/r9/r13 (same barrier positions, stage-after-barrier, buffer parity):
// V-regs are read from buf(kt) before the next barrier, so the restage of
// that buffer remains race-free by the same argument. Ping-pong PipeTile
// structs with named members (rule #20: no runtime-indexed state).
// ---------------------------------------------------------------------------
struct PipeTile {
    f16v c0, c1;
    s8v v0, v1, v2, v3, v4, v5, v6, v7;
    int boff;
};

__global__ __launch_bounds__(128, 2) void flash_kernel(const unsigned short* __restrict__ xb,
                                                       const unsigned short* __restrict__ xbT,
                                                       float* __restrict__ out) {
    __shared__ __align__(16) char lds[32768];

    const int id = blockIdx.x;
    const int bh = id & (BH - 1);
    const int t5 = id >> 5;                    // 0..31
    const int rr = t5 >> 3, uu = t5 & 7;
    // quad-balanced (r11-verified): per-CU quad sums to 66 iters
    const int qt = (rr == 0) ? (31 - uu) : (rr == 1) ? (16 + uu)
                 : (rr == 2) ? (15 - uu) : uu;
    const int b = bh >> 4, h = bh & (NHEAD - 1);
    const int tid = threadIdx.x;
    const int w = tid >> 6;                            // wave 0,1
    const int lane = tid & 63;
    const int qh = lane & 31;                          // MFMA m/n index (32)
    const int hh = lane >> 5;                          // half 0/1
    const int qbase = qt * 64;

    const unsigned short* xbh = xb + (size_t)b * SEQ * DMODEL + h * HD;
    const unsigned short* xTh = xbT + (size_t)bh * HD * SEQ;

    // Q fragments (B-operand): q-row = qbase + w*32 + qh, d = c*16 + hh*8 + j
    const int qrow = qbase + w * 32 + qh;
    const s8v qf0 = *(const s8v*)(xbh + (size_t)qrow * DMODEL + 0 * 16 + hh * 8);
    const s8v qf1 = *(const s8v*)(xbh + (size_t)qrow * DMODEL + 1 * 16 + hh * 8);
    const s8v qf2 = *(const s8v*)(xbh + (size_t)qrow * DMODEL + 2 * 16 + hh * 8);
    const s8v qf3 = *(const s8v*)(xbh + (size_t)qrow * DMODEL + 3 * 16 + hh * 8);

    // K A-frag / V^T B-frag LDS byte offsets (r12/r13-verified formulas)
    int kbo[2][4], vbo[2][4];
#pragma unroll
    for (int i2 = 0; i2 < 2; ++i2)
#pragma unroll
        for (int c = 0; c < 4; ++c) {
            kbo[i2][c] = (i2 * 32 + qh) * 128 + (((2 * c + hh) ^ (qh & 7)) * 16);
            vbo[i2][c] = 8192 + (i2 * 32 + qh) * 128 + (((2 * c + hh) ^ (qh & 7)) * 16);
        }

    f16v o0 = {0,0,0,0,0,0,0,0,0,0,0,0,0,0,0,0};
    f16v o1 = o0;
    float lsum = 0.0f;

    const int sr = lane >> 3;   // staging: row within 8-row chunk
    const int sc = lane & 7;    // staging: 16B slot within row

    // phase 1 of the pipeline: QK^T MFMAs + V-frags -> registers
    auto qkload = [&](PipeTile& T, int kt) {
        const char* buf = lds + ((kt & 1) << 14);
        T.boff = qbase + w * 32 - kt * 64;   // wave-uniform, >= 0
        f16v c0 = {0,0,0,0,0,0,0,0,0,0,0,0,0,0,0,0};
        f16v c1 = c0;
        __builtin_amdgcn_s_setprio(1);
        c0 = __builtin_amdgcn_mfma_f32_32x32x16_bf16(*(const s8v*)(buf + kbo[0][0]), qf0, c0, 0, 0, 0);
        c0 = __builtin_amdgcn_mfma_f32_32x32x16_bf16(*(const s8v*)(buf + kbo[0][1]), qf1, c0, 0, 0, 0);
        c0 = __builtin_amdgcn_mfma_f32_32x32x16_bf16(*(const s8v*)(buf + kbo[0][2]), qf2, c0, 0, 0, 0);
        c0 = __builtin_amdgcn_mfma_f32_32x32x16_bf16(*(const s8v*)(buf + kbo[0][3]), qf3, c0, 0, 0, 0);
        c1 = __builtin_amdgcn_mfma_f32_32x32x16_bf16(*(const s8v*)(buf + kbo[1][0]), qf0, c1, 0, 0, 0);
        c1 = __builtin_amdgcn_mfma_f32_32x32x16_bf16(*(const s8v*)(buf + kbo[1][1]), qf1, c1, 0, 0, 0);
        c1 = __builtin_amdgcn_mfma_f32_32x32x16_bf16(*(const s8v*)(buf + kbo[1][2]), qf2, c1, 0, 0, 0);
        c1 = __builtin_amdgcn_mfma_f32_32x32x16_bf16(*(const s8v*)(buf + kbo[1][3]), qf3, c1, 0, 0, 0);
        __builtin_amdgcn_s_setprio(0);
        T.c0 = c0; T.c1 = c1;
        T.v0 = *(const s8v*)(buf + vbo[0][0]);
        T.v1 = *(const s8v*)(buf + vbo[1][0]);
        T.v2 = *(const s8v*)(buf + vbo[0][1]);
        T.v3 = *(const s8v*)(buf + vbo[1][1]);
        T.v4 = *(const s8v*)(buf + vbo[0][2]);
        T.v5 = *(const s8v*)(buf + vbo[1][2]);
        T.v6 = *(const s8v*)(buf + vbo[0][3]);
        T.v7 = *(const s8v*)(buf + vbo[1][3]);
    };

    // phase 2 (register-only): softmax + T12 redistribution + PV
    auto finish = [&](const PipeTile& T) {
        float p0[16], p1[16];
#pragma unroll
        for (int e = 0; e < 16; ++e) {
            p0[e] = __builtin_amdgcn_exp2f(T.c0[e]);
            p1[e] = __builtin_amdgcn_exp2f(T.c1[e]);
        }
        if (!(T.boff >= 63)) {   // wave-uniform: only the diagonal k-tile
            const int qlim = T.boff + qh;
#pragma unroll
            for (int e = 0; e < 16; ++e) {
                const int kl = (e & 3) + 8 * (e >> 2) + 4 * hh;
                p0[e] = (kl <= qlim) ? p0[e] : 0.0f;
                p1[e] = (kl + 32 <= qlim) ? p1[e] : 0.0f;
            }
        }
#pragma unroll
        for (int e = 0; e < 16; ++e) lsum += p0[e] + p1[e];

        unsigned u0[8], u1[8];
#pragma unroll
        for (int m = 0; m < 8; ++m) {
            u0[m] = pk_bf16(p0[2 * m], p0[2 * m + 1]);
            u1[m] = pk_bf16(p1[2 * m], p1[2 * m + 1]);
        }
        u4v pw0, pw1, pw2, pw3;
        {
            unsigned a, b2;
            a = u0[0]; b2 = u0[2]; pl32swap(a, b2); pw0[0] = a; pw0[2] = b2;
            a = u0[1]; b2 = u0[3]; pl32swap(a, b2); pw0[1] = a; pw0[3] = b2;
            a = u0[4]; b2 = u0[6]; pl32swap(a, b2); pw1[0] = a; pw1[2] = b2;
            a = u0[5]; b2 = u0[7]; pl32swap(a, b2); pw1[1] = a; pw1[3] = b2;
            a = u1[0]; b2 = u1[2]; pl32swap(a, b2); pw2[0] = a; pw2[2] = b2;
            a = u1[1]; b2 = u1[3]; pl32swap(a, b2); pw2[1] = a; pw2[3] = b2;
            a = u1[4]; b2 = u1[6]; pl32swap(a, b2); pw3[0] = a; pw3[2] = b2;
            a = u1[5]; b2 = u1[7]; pl32swap(a, b2); pw3[1] = a; pw3[3] = b2;
        }
        const s8v pa0 = __builtin_bit_cast(s8v, pw0);
        const s8v pa1 = __builtin_bit_cast(s8v, pw1);
        const s8v pa2 = __builtin_bit_cast(s8v, pw2);
        const s8v pa3 = __builtin_bit_cast(s8v, pw3);

        __builtin_amdgcn_s_setprio(1);
        o0 = __builtin_amdgcn_mfma_f32_32x32x16_bf16(pa0, T.v0, o0, 0, 0, 0);
        o1 = __builtin_amdgcn_mfma_f32_32x32x16_bf16(pa0, T.v1, o1, 0, 0, 0);
        o0 = __builtin_amdgcn_mfma_f32_32x32x16_bf16(pa1, T.v2, o0, 0, 0, 0);
        o1 = __builtin_amdgcn_mfma_f32_32x32x16_bf16(pa1, T.v3, o1, 0, 0, 0);
        o0 = __builtin_amdgcn_mfma_f32_32x32x16_bf16(pa2, T.v4, o0, 0, 0, 0);
        o1 = __builtin_amdgcn_mfma_f32_32x32x16_bf16(pa2, T.v5, o1, 0, 0, 0);
        o0 = __builtin_amdgcn_mfma_f32_32x32x16_bf16(pa3, T.v6, o0, 0, 0, 0);
        o1 = __builtin_amdgcn_mfma_f32_32x32x16_bf16(pa3, T.v7, o1, 0, 0, 0);
        __builtin_amdgcn_s_setprio(0);
    };

    PipeTile tA, tB;

    // prologue: tile 0 staged + drained; prefetch tile 1; QK(0) in flight
    stage_tile2(xbh, xTh, lds, 0, 0, w, sr, sc);
    __syncthreads();
    if (qt > 0)
        stage_tile2(xbh, xTh, lds, 1 << 14, 64, w, sr, sc);
    qkload(tA, 0);

    int kt = 1;
    for (; kt + 1 <= qt; kt += 2) {
        // step: new -> tB, finish tA
        __syncthreads();   // drains stage(kt); all waves done reading buf(kt-1)
        if (kt < qt)
            stage_tile2(xbh, xTh, lds, ((kt + 1) & 1) << 14, (kt + 1) * 64, w, sr, sc);
        qkload(tB, kt);
        finish(tA);
        // step: new -> tA, finish tB
        __syncthreads();
        if (kt + 1 < qt)
            stage_tile2(xbh, xTh, lds, (kt & 1) << 14, (kt + 2) * 64, w, sr, sc);
        qkload(tA, kt + 1);
        finish(tB);
    }
    if (kt <= qt) {        // one tile remaining (kt == qt)
        __syncthreads();
        qkload(tB, kt);
        finish(tA);
        finish(tB);
    } else {
        finish(tA);
    }

    // ---- epilogue: l[q] = lsum(h0)+lsum(h1); lanes 0..31 hold l[qh] ----
    lsum += __shfl_xor(lsum, 32, 64);
    float invr[16];
#pragma unroll
    for (int e = 0; e < 16; ++e) {
        const int rowq = (e & 3) + 8 * (e >> 2) + 4 * hh;
        invr[e] = 1.0f / __shfl(lsum, rowq, 64);
    }

    float* outh = out + (size_t)b * SEQ * DMODEL + h * HD;
#pragma unroll
    for (int e = 0; e < 16; ++e) {
        const int rowq = (e & 3) + 8 * (e >> 2) + 4 * hh;
        const size_t ro = (size_t)(qbase + w * 32 + rowq) * DMODEL;
        outh[ro + 0 * 32 + qh] = o0[e] * invr[e];
        outh[ro + 1 * 32 + qh] = o1[e] * invr[e];
    }
}

// ---------------------------------------------------------------------------
// Fallback (round-1 fp32 kernel, known-correct) if workspace is too small.
// ---------------------------------------------------------------------------
#define KT 32
#define QR 16
#define LDS_STRIDE 68

__global__ __launch_bounds__(64, 2)
void attn_fp32_kernel(const float* __restrict__ x, float* __restrict__ out) {
    __shared__ float kv[KT * LDS_STRIDE];
    const int id = blockIdx.x;
    const int bh = id & (BATCH * NHEAD - 1);
    const int qt = (SEQ / QR - 1) - (id >> 5);
    const int b = bh >> 4, h = bh & (NHEAD - 1);
    const int lane = threadIdx.x;
    const int row = lane & (QR - 1);
    const int slice = lane >> 4;
    const int qrow = qt * QR + row;
    const float* xh = x + (size_t)b * SEQ * DMODEL + (size_t)h * HD;
    float q[HD], o[HD];
    const float4* qp = (const float4*)(xh + (size_t)qrow * DMODEL);
#pragma unroll
    for (int i = 0; i < HD / 4; ++i) {
        float4 v = qp[i];
        q[4*i+0] = v.x * 0.125f; q[4*i+1] = v.y * 0.125f;
        q[4*i+2] = v.z * 0.125f; q[4*i+3] = v.w * 0.125f;
    }
#pragma unroll
    for (int d = 0; d < HD; ++d) o[d] = 0.0f;
    float l = 0.0f;
    const int kend = qt * QR + QR;
    for (int kt0 = 0; kt0 < kend; kt0 += KT) {
        __syncthreads();
#pragma unroll
        for (int i = 0; i < (KT * HD / 4) / 64; ++i) {
            int idx = i * 64 + lane;
            int r = idx >> 4, cc = idx & 15;
            *(float4*)(kv + r * LDS_STRIDE + cc * 4) =
                *(const float4*)(xh + (size_t)(kt0 + r) * DMODEL + cc * 4);
        }
        __syncthreads();
#pragma unroll 2
        for (int jj = 0; jj < KT / 4; ++jj) {
            const int j = jj * 4 + slice;
            const float* kr = kv + j * LDS_STRIDE;
            float a0 = 0.f, a1 = 0.f, a2 = 0.f, a3 = 0.f;
#pragma unroll
            for (int dq = 0; dq < 16; ++dq) {
                float4 kk = ((const float4*)kr)[dq];
                a0 = fmaf(q[4*dq+0], kk.x, a0); a1 = fmaf(q[4*dq+1], kk.y, a1);
                a2 = fmaf(q[4*dq+2], kk.z, a2); a3 = fmaf(q[4*dq+3], kk.w, a3);
            }
            float p = __expf((a0 + a1) + (a2 + a3));
            p = (kt0 + j <= qrow) ? p : 0.0f;
            l += p;
#pragma unroll
            for (int dq = 0; dq < 16; ++dq) {
                float4 vv = ((const float4*)kr)[dq];
                o[4*dq+0] = fmaf(p, vv.x, o[4*dq+0]); o[4*dq+1] = fmaf(p, vv.y, o[4*dq+1]);
                o[4*dq+2] = fmaf(p, vv.z, o[4*dq+2]); o[4*dq+3] = fmaf(p, vv.w, o[4*dq+3]);
            }
        }
    }
    l += __shfl_xor(l, 16, 64);
    l += __shfl_xor(l, 32, 64);
#pragma unroll
    for (int d = 0; d < HD; ++d) {
        o[d] += __shfl_xor(o[d], 16, 64);
        o[d] += __shfl_xor(o[d], 32, 64);
    }
    if (slice == 0) {
        const float invl = 1.0f / l;
        float4* op = (float4*)(out + ((size_t)b * SEQ + qrow) * DMODEL + (size_t)h * HD);
#pragma unroll
        for (int i = 0; i < HD / 4; ++i) {
            float4 v;
            v.x = o[4*i+0] * invl; v.y = o[4*i+1] * invl;
            v.z = o[4*i+2] * invl; v.w = o[4*i+3] * invl;
            op[i] = v;
        }
    }
}

extern "C" void kernel_launch(void* const* d_in, const int* in_sizes, int n_in,
                              void* d_out, int out_size, void* d_ws, size_t ws_size,
                              hipStream_t stream) {
    const float* x = (const float*)d_in[0];
    float* out = (float*)d_out;
    const size_t nXb = (size_t)BATCH * SEQ * DMODEL;            // u16 elems
    const size_t need = 2 * nXb * 2;                            // xb + xbT
    if (ws_size >= need) {
        unsigned short* xb  = (unsigned short*)d_ws;
        unsigned short* xbT = xb + nXb;
        hipLaunchKernelGGL(prep_kernel, dim3(BH * SEQ / 32), dim3(256), 0, stream,
                           x, xb, xbT);
        hipLaunchKernelGGL(flash_kernel, dim3(BH * SEQ / 64), dim3(128), 0, stream,
                           xb, xbT, out);
    } else {
        hipLaunchKernelGGL(attn_fp32_kernel, dim3(BATCH * NHEAD * (SEQ / QR)), dim3(64), 0,
                           stream, x, out);
    }
}